// Round 1
// baseline (205775.781 us; speedup 1.0000x reference)
//
#include <hip/hip_runtime.h>
#include <math.h>

// LSTM_53171695124900: 2-layer LSTM, H=1024, I=64, O=2, T=4096, strictly
// sequential over T. Persistent cooperative-style kernel:
//   - 256 WGs x 256 threads (1 WG/CU, 1 wave/SIMD, VGPRs up to 512)
//   - all recurrent weights (W_hh1, W_ih2, W_hh2) live in VGPRs: 192 f32/thread
//   - WG w owns hidden units [4w,4w+4) of BOTH layers; wave index = gate (i,f,g,o)
//   - each gate row's 1024-dot: 16 lanes x 64 FMAs + 4-step shfl_xor reduce
//   - h1/h2 double-buffered in d_ws; custom pull-style grid barrier (per-WG
//     monotone phase flags, agent-scope fences handle cross-XCD L2 coherence)
//   - d_ws barrier/h state zeroed each call via hipMemsetAsync (re-poison safe)
//   - out[t] (2 floats) computed by WG0 off the critical path in step t+1

#define HID 1024
#define DIN 64
#define TSTEPS 4096
#define NWG 256
#define TPB 256

// ws layout in floats
#define WS_H1 0            // 2 * 1024 floats (double-buffered h1)
#define WS_H2 2048         // 2 * 1024 floats (double-buffered h2)
#define WS_FLAGS 4096      // 256 uints (barrier phase flags)
#define WS_ZERO_BYTES ((4096 + 256) * sizeof(float))

__device__ __forceinline__ float sigmoid_f(float v) {
    return 1.0f / (1.0f + __expf(-v));
}
__device__ __forceinline__ float tanh_f(float v) {
    return 2.0f / (1.0f + __expf(-2.0f * v)) - 1.0f;
}

// Decentralized grid barrier: every WG publishes a monotonically increasing
// phase; every thread polls exactly one WG's flag (NWG == TPB == 256).
// Release fence before publish (drains stores + L2 writeback so other XCDs
// see our h values); acquire fence after (invalidate L1/L2 so our next loads
// are fresh). ">=" compare: a fast WG may already be one phase ahead.
__device__ __forceinline__ void grid_barrier(unsigned* flags, unsigned ph,
                                             int tid, int wg)
{
    __builtin_amdgcn_fence(__ATOMIC_RELEASE, "agent");
    __syncthreads();
    if (tid == 0)
        __hip_atomic_store(&flags[wg], ph, __ATOMIC_RELEASE,
                           __HIP_MEMORY_SCOPE_AGENT);
    int guard = 0;
    while (__hip_atomic_load(&flags[tid], __ATOMIC_RELAXED,
                             __HIP_MEMORY_SCOPE_AGENT) < ph) {
        if (++guard > (1 << 22)) break;  // hang insurance only
    }
    __syncthreads();
    __builtin_amdgcn_fence(__ATOMIC_ACQUIRE, "agent");
}

__global__ __launch_bounds__(TPB, 1) void lstm_persistent(
    const float* __restrict__ x,
    const float* __restrict__ Wih1, const float* __restrict__ Whh1,
    const float* __restrict__ bih1, const float* __restrict__ bhh1,
    const float* __restrict__ Wih2, const float* __restrict__ Whh2,
    const float* __restrict__ bih2, const float* __restrict__ bhh2,
    const float* __restrict__ Wout, const float* __restrict__ bout,
    float* __restrict__ out, float* __restrict__ ws)
{
    const int wg    = blockIdx.x;    // 0..255
    const int tid   = threadIdx.x;   // 0..255
    const int wave  = tid >> 6;      // gate type: 0=i 1=f 2=g 3=o
    const int lane  = tid & 63;
    const int rsub  = lane >> 4;     // local unit 0..3
    const int c     = lane & 15;     // k-chunk index
    const int unit  = (wg << 2) + rsub;   // global hidden unit
    const int row   = wave * HID + unit;  // gate row in [0,4096)
    const int kbase = c << 6;             // 64 * c

    float* h1buf = ws + WS_H1;
    float* h2buf = ws + WS_H2;
    unsigned* flags = (unsigned*)(ws + WS_FLAGS);

    // ---- load persistent register weights (one-time, ~48MB total) ----
    float w1[64], w2[64], w3[64];  // W_hh1 / W_ih2 / W_hh2 row chunks
    {
        const float4* p1 = (const float4*)(Whh1 + (size_t)row * HID + kbase);
        const float4* p2 = (const float4*)(Wih2 + (size_t)row * HID + kbase);
        const float4* p3 = (const float4*)(Whh2 + (size_t)row * HID + kbase);
        #pragma unroll
        for (int j = 0; j < 16; ++j) {
            float4 a = p1[j];
            w1[4*j+0]=a.x; w1[4*j+1]=a.y; w1[4*j+2]=a.z; w1[4*j+3]=a.w;
        }
        #pragma unroll
        for (int j = 0; j < 16; ++j) {
            float4 a = p2[j];
            w2[4*j+0]=a.x; w2[4*j+1]=a.y; w2[4*j+2]=a.z; w2[4*j+3]=a.w;
        }
        #pragma unroll
        for (int j = 0; j < 16; ++j) {
            float4 a = p3[j];
            w3[4*j+0]=a.x; w3[4*j+1]=a.y; w3[4*j+2]=a.z; w3[4*j+3]=a.w;
        }
    }
    // W_ih1 chunk: this thread covers x[4c .. 4c+4) of its row's 64-dot
    const float4 wx = *(const float4*)(Wih1 + (size_t)row * DIN + (c << 2));
    const float bsum1 = bih1[row] + bhh1[row];
    const float bsum2 = bih2[row] + bhh2[row];
    // W_out fragment for WG0's out-task (thread covers h2[4*tid .. +4))
    const float4 wo0 = *(const float4*)(Wout + (tid << 2));
    const float4 wo1 = *(const float4*)(Wout + HID + (tid << 2));
    const float bo0 = bout[0], bo1 = bout[1];

    __shared__ float gates[4][4];   // [gate][unit]
    __shared__ float c1s[4], c2s[4];
    __shared__ float red0[4], red1[4];
    if (tid < 4) { c1s[tid] = 0.0f; c2s[tid] = 0.0f; }
    __syncthreads();

    unsigned ph = 0;

    for (int t = 0; t < TSTEPS; ++t) {
        const int cur = t & 1, prv = cur ^ 1;

        // ---- WG0 side-task: out[t-1] = W_out @ h2(t-1) + b_out ----
        // h2(t-1) sits in h2buf[prv], stable all of step t (synced at last
        // barrier). Off the critical path of the recurrence.
        if (wg == 0 && t > 0) {
            const float* h2p = h2buf + prv * HID;
            float4 hv = *(const float4*)(h2p + (tid << 2));
            float p0 = wo0.x*hv.x + wo0.y*hv.y + wo0.z*hv.z + wo0.w*hv.w;
            float p1 = wo1.x*hv.x + wo1.y*hv.y + wo1.z*hv.z + wo1.w*hv.w;
            #pragma unroll
            for (int m = 1; m < 64; m <<= 1) {
                p0 += __shfl_xor(p0, m);
                p1 += __shfl_xor(p1, m);
            }
            if (lane == 0) { red0[wave] = p0; red1[wave] = p1; }
            __syncthreads();
            if (tid == 0) {
                out[2*(t-1)+0] = red0[0]+red0[1]+red0[2]+red0[3] + bo0;
                out[2*(t-1)+1] = red1[0]+red1[1]+red1[2]+red1[3] + bo1;
            }
        }

        // ---- phase 1: layer-1 gates from h1(t-1) and x[t] ----
        {
            const float4* hp = (const float4*)(h1buf + prv * HID + kbase);
            float a0=0.f, a1=0.f, a2=0.f, a3=0.f;
            #pragma unroll
            for (int j = 0; j < 16; ++j) {
                float4 hv = hp[j];
                a0 = fmaf(w1[4*j+0], hv.x, a0);
                a1 = fmaf(w1[4*j+1], hv.y, a1);
                a2 = fmaf(w1[4*j+2], hv.z, a2);
                a3 = fmaf(w1[4*j+3], hv.w, a3);
            }
            const float4 xv = *(const float4*)(x + (size_t)t * DIN + (c << 2));
            a0 = fmaf(wx.x, xv.x, a0);
            a1 = fmaf(wx.y, xv.y, a1);
            a2 = fmaf(wx.z, xv.z, a2);
            a3 = fmaf(wx.w, xv.w, a3);
            float acc = (a0 + a1) + (a2 + a3);
            acc += __shfl_xor(acc, 1);
            acc += __shfl_xor(acc, 2);
            acc += __shfl_xor(acc, 4);
            acc += __shfl_xor(acc, 8);
            if (c == 0) {
                float v = acc + bsum1;
                gates[wave][rsub] = (wave == 2) ? tanh_f(v) : sigmoid_f(v);
            }
            __syncthreads();
            if (tid < 4) {
                float iv = gates[0][tid], fv = gates[1][tid];
                float gv = gates[2][tid], ov = gates[3][tid];
                float cn = fv * c1s[tid] + iv * gv;
                c1s[tid] = cn;
                float hn = ov * tanh_f(cn);
                __hip_atomic_store(h1buf + cur * HID + (wg << 2) + tid, hn,
                                   __ATOMIC_RELAXED, __HIP_MEMORY_SCOPE_AGENT);
            }
        }
        grid_barrier(flags, ++ph, tid, wg);

        // ---- phase 2: layer-2 gates from h1(t) and h2(t-1) ----
        {
            const float4* hp1 = (const float4*)(h1buf + cur * HID + kbase);
            const float4* hp2 = (const float4*)(h2buf + prv * HID + kbase);
            float a0=0.f, a1=0.f, a2=0.f, a3=0.f;
            #pragma unroll
            for (int j = 0; j < 16; ++j) {
                float4 hv = hp1[j];
                a0 = fmaf(w2[4*j+0], hv.x, a0);
                a1 = fmaf(w2[4*j+1], hv.y, a1);
                a2 = fmaf(w2[4*j+2], hv.z, a2);
                a3 = fmaf(w2[4*j+3], hv.w, a3);
            }
            #pragma unroll
            for (int j = 0; j < 16; ++j) {
                float4 hv = hp2[j];
                a0 = fmaf(w3[4*j+0], hv.x, a0);
                a1 = fmaf(w3[4*j+1], hv.y, a1);
                a2 = fmaf(w3[4*j+2], hv.z, a2);
                a3 = fmaf(w3[4*j+3], hv.w, a3);
            }
            float acc = (a0 + a1) + (a2 + a3);
            acc += __shfl_xor(acc, 1);
            acc += __shfl_xor(acc, 2);
            acc += __shfl_xor(acc, 4);
            acc += __shfl_xor(acc, 8);
            if (c == 0) {
                float v = acc + bsum2;
                gates[wave][rsub] = (wave == 2) ? tanh_f(v) : sigmoid_f(v);
            }
            __syncthreads();
            if (tid < 4) {
                float iv = gates[0][tid], fv = gates[1][tid];
                float gv = gates[2][tid], ov = gates[3][tid];
                float cn = fv * c2s[tid] + iv * gv;
                c2s[tid] = cn;
                float hn = ov * tanh_f(cn);
                __hip_atomic_store(h2buf + cur * HID + (wg << 2) + tid, hn,
                                   __ATOMIC_RELAXED, __HIP_MEMORY_SCOPE_AGENT);
            }
        }
        grid_barrier(flags, ++ph, tid, wg);
    }

    // ---- epilogue: out[T-1] ----
    if (wg == 0) {
        const float* h2p = h2buf + ((TSTEPS - 1) & 1) * HID;
        float4 hv = *(const float4*)(h2p + (tid << 2));
        float p0 = wo0.x*hv.x + wo0.y*hv.y + wo0.z*hv.z + wo0.w*hv.w;
        float p1 = wo1.x*hv.x + wo1.y*hv.y + wo1.z*hv.z + wo1.w*hv.w;
        #pragma unroll
        for (int m = 1; m < 64; m <<= 1) {
            p0 += __shfl_xor(p0, m);
            p1 += __shfl_xor(p1, m);
        }
        if (lane == 0) { red0[wave] = p0; red1[wave] = p1; }
        __syncthreads();
        if (tid == 0) {
            out[2*(TSTEPS-1)+0] = red0[0]+red0[1]+red0[2]+red0[3] + bo0;
            out[2*(TSTEPS-1)+1] = red1[0]+red1[1]+red1[2]+red1[3] + bo1;
        }
    }
}

extern "C" void kernel_launch(void* const* d_in, const int* in_sizes, int n_in,
                              void* d_out, int out_size, void* d_ws, size_t ws_size,
                              hipStream_t stream)
{
    const float* x    = (const float*)d_in[0];
    const float* Wih1 = (const float*)d_in[1];
    const float* Whh1 = (const float*)d_in[2];
    const float* bih1 = (const float*)d_in[3];
    const float* bhh1 = (const float*)d_in[4];
    const float* Wih2 = (const float*)d_in[5];
    const float* Whh2 = (const float*)d_in[6];
    const float* bih2 = (const float*)d_in[7];
    const float* bhh2 = (const float*)d_in[8];
    const float* Wout = (const float*)d_in[9];
    const float* bout = (const float*)d_in[10];
    float* out = (float*)d_out;
    float* ws  = (float*)d_ws;

    // zero h-state + barrier flags (d_ws is re-poisoned to 0xAA before every
    // timed call; memset is graph-capture safe)
    hipMemsetAsync(d_ws, 0, WS_ZERO_BYTES, stream);

    hipLaunchKernelGGL(lstm_persistent, dim3(NWG), dim3(TPB), 0, stream,
                       x, Wih1, Whh1, bih1, bhh1,
                       Wih2, Whh2, bih2, bhh2,
                       Wout, bout, out, ws);
}

// Round 2
// 28492.743 us; speedup vs baseline: 7.2220x; 7.2220x over previous
//
#include <hip/hip_runtime.h>
#include <math.h>

// LSTM_53171695124900: 2-layer LSTM, H=1024, I=64, O=2, T=4096.
// Persistent kernel, 256 WGs x 256 threads (1 WG/CU, 1 wave/SIMD).
// Round-2 changes vs round-1:
//  - weights truly pinned in VGPRs via empty asm "+v" (defeats remat; r1 had
//    VGPR=132 -> weights re-streamed from L3 every phase)
//  - fence-free grid barrier: all cross-WG traffic is relaxed agent-scope
//    atomics (coherent at L3, no buffer_inv/buffer_wbl2 L2 nukes);
//    producer order via explicit s_waitcnt vmcnt(0)
//  - ONE barrier/step: phase p computes h1(p) AND h2(p-1) concurrently
//    (both depend only on phase p-1 data); 4097 phases total
//  - h vectors staged via LDS (row-padded +4 dwords -> 2-way bank conflicts)

#define HID 1024
#define DIN 64
#define TSTEPS 4096
#define NWG 256
#define TPB 256

// ws layout (floats)
#define WS_H1 0            // 2 x 1024 (double-buffered h1)
#define WS_H2 2048         // 2 x 1024 (double-buffered h2)
#define WS_FLAGS 4096      // 256 uints (barrier phase flags)
#define WS_ZERO_BYTES ((4096 + 256) * sizeof(float))

__device__ __forceinline__ float sigmoid_f(float v) {
    return 1.0f / (1.0f + __expf(-v));
}
__device__ __forceinline__ float tanh_f(float v) {
    return 2.0f / (1.0f + __expf(-2.0f * v)) - 1.0f;
}

// relaxed agent-scope atomics: coherent at the agent coherence point (L3),
// bypass non-coherent L1/L2, emit NO cache-maintenance instructions
__device__ __forceinline__ void st_agent(float* p, float v) {
    __hip_atomic_store(p, v, __ATOMIC_RELAXED, __HIP_MEMORY_SCOPE_AGENT);
}
__device__ __forceinline__ float ld_agent(const float* p) {
    return __hip_atomic_load(p, __ATOMIC_RELAXED, __HIP_MEMORY_SCOPE_AGENT);
}

__global__ __launch_bounds__(TPB, 1) void lstm_persistent(
    const float* __restrict__ x,
    const float* __restrict__ Wih1, const float* __restrict__ Whh1,
    const float* __restrict__ bih1, const float* __restrict__ bhh1,
    const float* __restrict__ Wih2, const float* __restrict__ Whh2,
    const float* __restrict__ bih2, const float* __restrict__ bhh2,
    const float* __restrict__ Wout, const float* __restrict__ bout,
    float* __restrict__ out, float* __restrict__ ws)
{
    const int wg   = blockIdx.x;     // 0..255
    const int tid  = threadIdx.x;    // 0..255
    const int wave = tid >> 6;       // gate: 0=i 1=f 2=g 3=o
    const int lane = tid & 63;
    const int rsub = lane >> 4;      // local unit 0..3
    const int c    = lane & 15;      // k-chunk 0..15
    const int row  = wave * HID + (wg << 2) + rsub;  // gate row in [0,4096)
    const int kbase = c << 6;

    float* h1buf = ws + WS_H1;
    float* h2buf = ws + WS_H2;
    unsigned* flags = (unsigned*)(ws + WS_FLAGS);

    // ---- one-time load of persistent register weights ----
    float w1[64], w2[64], w3[64];   // W_hh1 / W_ih2 / W_hh2 row chunks
    {
        const float4* p1 = (const float4*)(Whh1 + (size_t)row * HID + kbase);
        const float4* p2 = (const float4*)(Wih2 + (size_t)row * HID + kbase);
        const float4* p3 = (const float4*)(Whh2 + (size_t)row * HID + kbase);
        #pragma unroll
        for (int j = 0; j < 16; ++j) {
            float4 a = p1[j];
            w1[4*j+0]=a.x; w1[4*j+1]=a.y; w1[4*j+2]=a.z; w1[4*j+3]=a.w;
        }
        #pragma unroll
        for (int j = 0; j < 16; ++j) {
            float4 a = p2[j];
            w2[4*j+0]=a.x; w2[4*j+1]=a.y; w2[4*j+2]=a.z; w2[4*j+3]=a.w;
        }
        #pragma unroll
        for (int j = 0; j < 16; ++j) {
            float4 a = p3[j];
            w3[4*j+0]=a.x; w3[4*j+1]=a.y; w3[4*j+2]=a.z; w3[4*j+3]=a.w;
        }
    }
    // pin: make values opaque so the compiler cannot rematerialize the loads
    #pragma unroll
    for (int j = 0; j < 64; ++j) {
        asm volatile("" : "+v"(w1[j]), "+v"(w2[j]), "+v"(w3[j]));
    }

    const float4 wx = *(const float4*)(Wih1 + (size_t)row * DIN + (c << 2));
    const float bsum1 = bih1[row] + bhh1[row];
    const float bsum2 = bih2[row] + bhh2[row];
    const float4 wo0 = *(const float4*)(Wout + (tid << 2));
    const float4 wo1 = *(const float4*)(Wout + HID + (tid << 2));
    const float bo0 = bout[0], bo1 = bout[1];

    // LDS: staged h vectors, row-padded (+4 dwords per 64-dword row)
    __shared__ __align__(16) float h1s[1088];
    __shared__ __align__(16) float h2s[1088];
    __shared__ float g1[4][4], g2[4][4];
    __shared__ float c1s[4], c2s[4];
    __shared__ float red0[4], red1[4];
    if (tid < 4) { c1s[tid] = 0.0f; c2s[tid] = 0.0f; }

    const int sdst = (tid << 2) + ((tid >> 4) << 2);  // 4t + 4*(t/16)
    const int sbase = 68 * c;                         // padded row base

    for (int p = 0; p <= TSTEPS; ++p) {
        const int cur = p & 1, prv = cur ^ 1;

        // ---- stage h1(p-1), h2(p-2) from global (slot prv) into LDS ----
        const float* s1 = h1buf + prv * HID + (tid << 2);
        const float* s2 = h2buf + prv * HID + (tid << 2);
        float a0 = ld_agent(s1+0), a1 = ld_agent(s1+1);
        float a2 = ld_agent(s1+2), a3 = ld_agent(s1+3);
        float b0 = ld_agent(s2+0), b1 = ld_agent(s2+1);
        float b2 = ld_agent(s2+2), b3 = ld_agent(s2+3);
        *(float4*)(h1s + sdst) = make_float4(a0, a1, a2, a3);
        *(float4*)(h2s + sdst) = make_float4(b0, b1, b2, b3);

        // ---- WG0 side-task: out(p-2) = Wout @ h2(p-2) + bout ----
        if (wg == 0 && p >= 2) {
            float q0 = wo0.x*b0 + wo0.y*b1 + wo0.z*b2 + wo0.w*b3;
            float q1 = wo1.x*b0 + wo1.y*b1 + wo1.z*b2 + wo1.w*b3;
            #pragma unroll
            for (int m = 1; m < 64; m <<= 1) {
                q0 += __shfl_xor(q0, m);
                q1 += __shfl_xor(q1, m);
            }
            if (lane == 0) { red0[wave] = q0; red1[wave] = q1; }
            __syncthreads();
            if (tid == 0) {
                out[2*(p-2)+0] = red0[0]+red0[1]+red0[2]+red0[3] + bo0;
                out[2*(p-2)+1] = red1[0]+red1[1]+red1[2]+red1[3] + bo1;
            }
        }
        __syncthreads();

        // ---- dots: accA = W_hh1 row . h1prev (+x term)  [layer 1, t=p]
        //            accB = W_ih2 row . h1prev + W_hh2 row . h2prev [layer 2, t=p-1]
        float a0s=0.f, a1s=0.f, a2s=0.f, a3s=0.f;
        float e0s=0.f, e1s=0.f, e2s=0.f, e3s=0.f;
        #pragma unroll
        for (int j = 0; j < 16; ++j) {
            float4 hv = *(const float4*)(h1s + sbase + 4*j);
            a0s = fmaf(w1[4*j+0], hv.x, a0s);
            a1s = fmaf(w1[4*j+1], hv.y, a1s);
            a2s = fmaf(w1[4*j+2], hv.z, a2s);
            a3s = fmaf(w1[4*j+3], hv.w, a3s);
            e0s = fmaf(w2[4*j+0], hv.x, e0s);
            e1s = fmaf(w2[4*j+1], hv.y, e1s);
            e2s = fmaf(w2[4*j+2], hv.z, e2s);
            e3s = fmaf(w2[4*j+3], hv.w, e3s);
            float4 gv = *(const float4*)(h2s + sbase + 4*j);
            e0s = fmaf(w3[4*j+0], gv.x, e0s);
            e1s = fmaf(w3[4*j+1], gv.y, e1s);
            e2s = fmaf(w3[4*j+2], gv.z, e2s);
            e3s = fmaf(w3[4*j+3], gv.w, e3s);
        }
        // x term (guard OOB at p==TSTEPS; result discarded there)
        {
            const int tx = (p < TSTEPS) ? p : 0;
            const float4 xv = *(const float4*)(x + (size_t)tx * DIN + (c << 2));
            a0s = fmaf(wx.x, xv.x, a0s);
            a1s = fmaf(wx.y, xv.y, a1s);
            a2s = fmaf(wx.z, xv.z, a2s);
            a3s = fmaf(wx.w, xv.w, a3s);
        }
        float accA = (a0s + a1s) + (a2s + a3s);
        float accB = (e0s + e1s) + (e2s + e3s);
        accA += __shfl_xor(accA, 1);  accB += __shfl_xor(accB, 1);
        accA += __shfl_xor(accA, 2);  accB += __shfl_xor(accB, 2);
        accA += __shfl_xor(accA, 4);  accB += __shfl_xor(accB, 4);
        accA += __shfl_xor(accA, 8);  accB += __shfl_xor(accB, 8);
        if (c == 0) {
            float vA = accA + bsum1;
            float vB = accB + bsum2;
            g1[wave][rsub] = (wave == 2) ? tanh_f(vA) : sigmoid_f(vA);
            g2[wave][rsub] = (wave == 2) ? tanh_f(vB) : sigmoid_f(vB);
        }
        __syncthreads();

        // ---- state updates + h publication (sc1 stores) ----
        if (p < TSTEPS && tid < 4) {
            float iv = g1[0][tid], fv = g1[1][tid];
            float gv = g1[2][tid], ov = g1[3][tid];
            float cn = fv * c1s[tid] + iv * gv;
            c1s[tid] = cn;
            st_agent(h1buf + cur * HID + (wg << 2) + tid, ov * tanh_f(cn));
        }
        if (p >= 1 && tid >= 4 && tid < 8) {
            int u = tid - 4;
            float iv = g2[0][u], fv = g2[1][u];
            float gv = g2[2][u], ov = g2[3][u];
            float cn = fv * c2s[u] + iv * gv;
            c2s[u] = cn;
            st_agent(h2buf + cur * HID + (wg << 2) + u, ov * tanh_f(cn));
        }

        // ---- fence-free grid barrier (publish phase p+1) ----
        // producer order: h stores (sc1) -> vmcnt(0) -> flag store (sc1).
        // tid 0..7 are all in wave 0, so wave 0's vmcnt covers the h stores.
        asm volatile("s_waitcnt vmcnt(0)" ::: "memory");
        if (tid == 0) {
            __hip_atomic_store(&flags[wg], (unsigned)(p + 1),
                               __ATOMIC_RELAXED, __HIP_MEMORY_SCOPE_AGENT);
        }
        {
            int guard = 0;
            while (__hip_atomic_load(&flags[tid], __ATOMIC_RELAXED,
                                     __HIP_MEMORY_SCOPE_AGENT) < (unsigned)(p + 1)) {
                if (++guard > (1 << 17)) break;  // hang insurance only
            }
        }
        asm volatile("" ::: "memory");
        __syncthreads();   // also protects LDS h1s/h2s reuse next phase
    }

    // ---- epilogue: out(T-1) from h2 slot (T&1) ----
    if (wg == 0) {
        const float* h2p = h2buf + (TSTEPS & 1) * HID + (tid << 2);
        float b0 = ld_agent(h2p+0), b1 = ld_agent(h2p+1);
        float b2 = ld_agent(h2p+2), b3 = ld_agent(h2p+3);
        float q0 = wo0.x*b0 + wo0.y*b1 + wo0.z*b2 + wo0.w*b3;
        float q1 = wo1.x*b0 + wo1.y*b1 + wo1.z*b2 + wo1.w*b3;
        #pragma unroll
        for (int m = 1; m < 64; m <<= 1) {
            q0 += __shfl_xor(q0, m);
            q1 += __shfl_xor(q1, m);
        }
        if (lane == 0) { red0[wave] = q0; red1[wave] = q1; }
        __syncthreads();
        if (tid == 0) {
            out[2*(TSTEPS-1)+0] = red0[0]+red0[1]+red0[2]+red0[3] + bo0;
            out[2*(TSTEPS-1)+1] = red1[0]+red1[1]+red1[2]+red1[3] + bo1;
        }
    }
}

extern "C" void kernel_launch(void* const* d_in, const int* in_sizes, int n_in,
                              void* d_out, int out_size, void* d_ws, size_t ws_size,
                              hipStream_t stream)
{
    const float* x    = (const float*)d_in[0];
    const float* Wih1 = (const float*)d_in[1];
    const float* Whh1 = (const float*)d_in[2];
    const float* bih1 = (const float*)d_in[3];
    const float* bhh1 = (const float*)d_in[4];
    const float* Wih2 = (const float*)d_in[5];
    const float* Whh2 = (const float*)d_in[6];
    const float* bih2 = (const float*)d_in[7];
    const float* bhh2 = (const float*)d_in[8];
    const float* Wout = (const float*)d_in[9];
    const float* bout = (const float*)d_in[10];
    float* out = (float*)d_out;
    float* ws  = (float*)d_ws;

    // zero h-state + barrier flags (ws is re-poisoned 0xAA before every call)
    hipMemsetAsync(d_ws, 0, WS_ZERO_BYTES, stream);

    hipLaunchKernelGGL(lstm_persistent, dim3(NWG), dim3(TPB), 0, stream,
                       x, Wih1, Whh1, bih1, bhh1,
                       Wih2, Whh2, bih2, bhh2,
                       Wout, bout, out, ws);
}

// Round 3
// 27161.337 us; speedup vs baseline: 7.5761x; 1.0490x over previous
//
#include <hip/hip_runtime.h>
#include <math.h>

// LSTM_53171695124900: 2-layer LSTM, H=1024, I=64, O=2, T=4096.
// Persistent kernel, 256 WGs x 512 threads (1 WG/CU, 2 waves/SIMD).
// Round-3 changes vs round-2:
//  - 512 thr/WG -> 96 weight floats/thread (fits 256-VGPR budget; r2's 192
//    floats @ 140 VGPRs were scratch-spilled: WRITE_SIZE showed +48MB spill,
//    ~4us/phase of L3 re-reads)
//  - rows split 32 lanes x 32 elems, 5-step shfl_xor reduce
//  - out[] via h2 history buffer + one-time epilogue (removes per-phase WG0
//    straggler that the grid barrier propagated); ws_size-guarded fallback
//  - same fence-free relaxed-agent-atomic barrier as r2 (passed, absmax 6e-5)

#define HID 1024
#define DIN 64
#define TSTEPS 4096
#define NWG 256
#define TPB 512

// ws layout (floats)
#define WS_H1 0              // 2 x 1024 (double-buffered h1)
#define WS_H2 2048           // 2 x 1024 (double-buffered h2)
#define WS_FLAGS 4096        // 256 uints (barrier phase flags)
#define WS_HIST 4352         // 4096 x 1024 h2 history (optional)
#define WS_ZERO_BYTES ((4096 + 256) * sizeof(float))
#define WS_HIST_BYTES ((size_t)(WS_HIST + (size_t)TSTEPS * HID) * sizeof(float))

__device__ __forceinline__ float sigmoid_f(float v) {
    return 1.0f / (1.0f + __expf(-v));
}
__device__ __forceinline__ float tanh_f(float v) {
    return 2.0f / (1.0f + __expf(-2.0f * v)) - 1.0f;
}

// relaxed agent-scope atomics: coherent at L3, bypass non-coherent L1/L2,
// no buffer_inv/buffer_wbl2 cache maintenance
__device__ __forceinline__ void st_agent(float* p, float v) {
    __hip_atomic_store(p, v, __ATOMIC_RELAXED, __HIP_MEMORY_SCOPE_AGENT);
}
__device__ __forceinline__ float ld_agent(const float* p) {
    return __hip_atomic_load(p, __ATOMIC_RELAXED, __HIP_MEMORY_SCOPE_AGENT);
}

__global__ __launch_bounds__(TPB, 2) void lstm_persistent(
    const float* __restrict__ x,
    const float* __restrict__ Wih1, const float* __restrict__ Whh1,
    const float* __restrict__ bih1, const float* __restrict__ bhh1,
    const float* __restrict__ Wih2, const float* __restrict__ Whh2,
    const float* __restrict__ bih2, const float* __restrict__ bhh2,
    const float* __restrict__ Wout, const float* __restrict__ bout,
    float* __restrict__ out, float* __restrict__ ws, int use_hist)
{
    const int wg   = blockIdx.x;          // 0..255
    const int tid  = threadIdx.x;         // 0..511
    const int wave = tid >> 6;            // 0..7
    const int lane = tid & 63;
    const int gate = tid >> 7;            // 0..3 (i,f,g,o)
    const int rsub = (tid >> 5) & 3;      // local unit 0..3
    const int c    = tid & 31;            // k-chunk 0..31 (32 elems each)
    const int row  = gate * HID + (wg << 2) + rsub;   // gate row in [0,4096)
    const int kbase = c << 5;

    float* h1buf = ws + WS_H1;
    float* h2buf = ws + WS_H2;
    unsigned* flags = (unsigned*)(ws + WS_FLAGS);
    float* h2hist = ws + WS_HIST;

    // ---- one-time load of persistent register weights (96 floats) ----
    float w1[32], w2[32], w3[32];   // W_hh1 / W_ih2 / W_hh2 row chunks
    {
        const float4* p1 = (const float4*)(Whh1 + (size_t)row * HID + kbase);
        const float4* p2 = (const float4*)(Wih2 + (size_t)row * HID + kbase);
        const float4* p3 = (const float4*)(Whh2 + (size_t)row * HID + kbase);
        #pragma unroll
        for (int j = 0; j < 8; ++j) {
            float4 a = p1[j];
            w1[4*j+0]=a.x; w1[4*j+1]=a.y; w1[4*j+2]=a.z; w1[4*j+3]=a.w;
        }
        #pragma unroll
        for (int j = 0; j < 8; ++j) {
            float4 a = p2[j];
            w2[4*j+0]=a.x; w2[4*j+1]=a.y; w2[4*j+2]=a.z; w2[4*j+3]=a.w;
        }
        #pragma unroll
        for (int j = 0; j < 8; ++j) {
            float4 a = p3[j];
            w3[4*j+0]=a.x; w3[4*j+1]=a.y; w3[4*j+2]=a.z; w3[4*j+3]=a.w;
        }
    }
    // pin values (defeat remat); 96 live floats vs 256-VGPR budget -> no spill
    #pragma unroll
    for (int j = 0; j < 32; ++j) {
        asm volatile("" : "+v"(w1[j]), "+v"(w2[j]), "+v"(w3[j]));
    }

    const float2 wx = *(const float2*)(Wih1 + (size_t)row * DIN + (c << 1));
    const float bsum1 = bih1[row] + bhh1[row];
    const float bsum2 = bih2[row] + bhh2[row];
    const float2 wo0 = *(const float2*)(Wout + (tid << 1));
    const float2 wo1 = *(const float2*)(Wout + HID + (tid << 1));
    const float bo0 = bout[0], bo1 = bout[1];

    // LDS: staged h vectors, stride-36 rows (32 data + 4 pad, 16B aligned)
    __shared__ __align__(16) float h1s[1152];
    __shared__ __align__(16) float h2s[1152];
    __shared__ float g1[4][4], g2[4][4];
    __shared__ float c1s[4], c2s[4];
    __shared__ float red0[8], red1[8];
    if (tid < 4) { c1s[tid] = 0.0f; c2s[tid] = 0.0f; }

    // element e=2*tid lands at 36*(e>>5) + (e&31)
    const int sdst = 36 * (tid >> 4) + ((tid << 1) & 31);
    const int sbase = 36 * c;

    for (int p = 0; p <= TSTEPS; ++p) {
        const int cur = p & 1, prv = cur ^ 1;

        // ---- stage h1(p-1), h2(p-2) (slot prv) into LDS ----
        const float* s1 = h1buf + prv * HID + (tid << 1);
        const float* s2 = h2buf + prv * HID + (tid << 1);
        float a0 = ld_agent(s1 + 0), a1 = ld_agent(s1 + 1);
        float b0 = ld_agent(s2 + 0), b1 = ld_agent(s2 + 1);
        *(float2*)(h1s + sdst) = make_float2(a0, a1);
        *(float2*)(h2s + sdst) = make_float2(b0, b1);

        // ---- fallback out-path: WG0 computes out(p-2) in-loop ----
        if (!use_hist && wg == 0 && p >= 2) {
            float q0 = wo0.x * b0 + wo0.y * b1;
            float q1 = wo1.x * b0 + wo1.y * b1;
            #pragma unroll
            for (int m = 1; m < 64; m <<= 1) {
                q0 += __shfl_xor(q0, m);
                q1 += __shfl_xor(q1, m);
            }
            if (lane == 0) { red0[wave] = q0; red1[wave] = q1; }
            __syncthreads();
            if (tid == 0) {
                float o0 = bo0, o1 = bo1;
                #pragma unroll
                for (int w = 0; w < 8; ++w) { o0 += red0[w]; o1 += red1[w]; }
                out[2*(p-2)+0] = o0;
                out[2*(p-2)+1] = o1;
            }
        }
        __syncthreads();

        // ---- dots: accA = Whh1 . h1prev (+ x)    [layer 1, t=p]
        //            accB = Wih2 . h1prev + Whh2 . h2prev  [layer 2, t=p-1]
        float a0s=0.f, a1s=0.f, a2s=0.f, a3s=0.f;
        float e0s=0.f, e1s=0.f, e2s=0.f, e3s=0.f;
        #pragma unroll
        for (int j = 0; j < 8; ++j) {
            float4 hv = *(const float4*)(h1s + sbase + 4*j);
            a0s = fmaf(w1[4*j+0], hv.x, a0s);
            a1s = fmaf(w1[4*j+1], hv.y, a1s);
            a2s = fmaf(w1[4*j+2], hv.z, a2s);
            a3s = fmaf(w1[4*j+3], hv.w, a3s);
            e0s = fmaf(w2[4*j+0], hv.x, e0s);
            e1s = fmaf(w2[4*j+1], hv.y, e1s);
            e2s = fmaf(w2[4*j+2], hv.z, e2s);
            e3s = fmaf(w2[4*j+3], hv.w, e3s);
            float4 gv = *(const float4*)(h2s + sbase + 4*j);
            e0s = fmaf(w3[4*j+0], gv.x, e0s);
            e1s = fmaf(w3[4*j+1], gv.y, e1s);
            e2s = fmaf(w3[4*j+2], gv.z, e2s);
            e3s = fmaf(w3[4*j+3], gv.w, e3s);
        }
        {
            const int tx = (p < TSTEPS) ? p : 0;
            const float2 xv = *(const float2*)(x + (size_t)tx * DIN + (c << 1));
            a0s = fmaf(wx.x, xv.x, a0s);
            a1s = fmaf(wx.y, xv.y, a1s);
        }
        float accA = (a0s + a1s) + (a2s + a3s);
        float accB = (e0s + e1s) + (e2s + e3s);
        accA += __shfl_xor(accA, 1);   accB += __shfl_xor(accB, 1);
        accA += __shfl_xor(accA, 2);   accB += __shfl_xor(accB, 2);
        accA += __shfl_xor(accA, 4);   accB += __shfl_xor(accB, 4);
        accA += __shfl_xor(accA, 8);   accB += __shfl_xor(accB, 8);
        accA += __shfl_xor(accA, 16);  accB += __shfl_xor(accB, 16);
        if (c == 0) {
            float vA = accA + bsum1;
            float vB = accB + bsum2;
            g1[gate][rsub] = (gate == 2) ? tanh_f(vA) : sigmoid_f(vA);
            g2[gate][rsub] = (gate == 2) ? tanh_f(vB) : sigmoid_f(vB);
        }
        __syncthreads();

        // ---- state updates + h publication ----
        if (p < TSTEPS && tid < 4) {
            float iv = g1[0][tid], fv = g1[1][tid];
            float gv = g1[2][tid], ov = g1[3][tid];
            float cn = fv * c1s[tid] + iv * gv;
            c1s[tid] = cn;
            st_agent(h1buf + cur * HID + (wg << 2) + tid, ov * tanh_f(cn));
        }
        if (p >= 1 && tid >= 4 && tid < 8) {
            int u = tid - 4;
            float iv = g2[0][u], fv = g2[1][u];
            float gv = g2[2][u], ov = g2[3][u];
            float cn = fv * c2s[u] + iv * gv;
            c2s[u] = cn;
            float hn = ov * tanh_f(cn);
            st_agent(h2buf + cur * HID + (wg << 2) + u, hn);
            if (use_hist)
                st_agent(h2hist + (size_t)(p - 1) * HID + (wg << 2) + u, hn);
        }

        // ---- fence-free grid barrier (publish p+1) ----
        // producer order: h stores -> vmcnt(0) -> flag store (all in wave 0)
        asm volatile("s_waitcnt vmcnt(0)" ::: "memory");
        if (tid == 0) {
            __hip_atomic_store(&flags[wg], (unsigned)(p + 1),
                               __ATOMIC_RELAXED, __HIP_MEMORY_SCOPE_AGENT);
        }
        {
            int guard = 0;
            while (__hip_atomic_load(&flags[tid & 255], __ATOMIC_RELAXED,
                                     __HIP_MEMORY_SCOPE_AGENT) < (unsigned)(p + 1)) {
                if (++guard > (1 << 17)) break;  // hang insurance only
            }
        }
        asm volatile("" ::: "memory");
        __syncthreads();   // also protects LDS reuse next phase
    }

    // ---- epilogue ----
    if (use_hist) {
        // WG w computes out[16w .. 16w+16): 2x 1024-dot per t across 512 thr
        for (int i = 0; i < 16; ++i) {
            const int t = (wg << 4) + i;
            const float* hp = h2hist + (size_t)t * HID + (tid << 1);
            float hv0 = ld_agent(hp + 0), hv1 = ld_agent(hp + 1);
            float q0 = wo0.x * hv0 + wo0.y * hv1;
            float q1 = wo1.x * hv0 + wo1.y * hv1;
            #pragma unroll
            for (int m = 1; m < 64; m <<= 1) {
                q0 += __shfl_xor(q0, m);
                q1 += __shfl_xor(q1, m);
            }
            if (lane == 0) { red0[wave] = q0; red1[wave] = q1; }
            __syncthreads();
            if (tid == 0) {
                float o0 = bo0, o1 = bo1;
                #pragma unroll
                for (int w = 0; w < 8; ++w) { o0 += red0[w]; o1 += red1[w]; }
                out[2*t+0] = o0;
                out[2*t+1] = o1;
            }
            __syncthreads();
        }
    } else if (wg == 0) {
        // out[T-1]: h2(T-1) lives in slot TSTEPS&1 == 0
        const float* hp = h2buf + (TSTEPS & 1) * HID + (tid << 1);
        float hv0 = ld_agent(hp + 0), hv1 = ld_agent(hp + 1);
        float q0 = wo0.x * hv0 + wo0.y * hv1;
        float q1 = wo1.x * hv0 + wo1.y * hv1;
        #pragma unroll
        for (int m = 1; m < 64; m <<= 1) {
            q0 += __shfl_xor(q0, m);
            q1 += __shfl_xor(q1, m);
        }
        if (lane == 0) { red0[wave] = q0; red1[wave] = q1; }
        __syncthreads();
        if (tid == 0) {
            float o0 = bo0, o1 = bo1;
            #pragma unroll
            for (int w = 0; w < 8; ++w) { o0 += red0[w]; o1 += red1[w]; }
            out[2*(TSTEPS-1)+0] = o0;
            out[2*(TSTEPS-1)+1] = o1;
        }
    }
}

extern "C" void kernel_launch(void* const* d_in, const int* in_sizes, int n_in,
                              void* d_out, int out_size, void* d_ws, size_t ws_size,
                              hipStream_t stream)
{
    const float* x    = (const float*)d_in[0];
    const float* Wih1 = (const float*)d_in[1];
    const float* Whh1 = (const float*)d_in[2];
    const float* bih1 = (const float*)d_in[3];
    const float* bhh1 = (const float*)d_in[4];
    const float* Wih2 = (const float*)d_in[5];
    const float* Whh2 = (const float*)d_in[6];
    const float* bih2 = (const float*)d_in[7];
    const float* bhh2 = (const float*)d_in[8];
    const float* Wout = (const float*)d_in[9];
    const float* bout = (const float*)d_in[10];
    float* out = (float*)d_out;
    float* ws  = (float*)d_ws;

    const int use_hist = (ws_size >= WS_HIST_BYTES) ? 1 : 0;

    // zero h-state + barrier flags (ws re-poisoned 0xAA before every call)
    hipMemsetAsync(d_ws, 0, WS_ZERO_BYTES, stream);

    hipLaunchKernelGGL(lstm_persistent, dim3(NWG), dim3(TPB), 0, stream,
                       x, Wih1, Whh1, bih1, bhh1,
                       Wih2, Whh2, bih2, bhh2,
                       Wout, bout, out, ws, use_hist);
}